// Round 2
// baseline (82286.841 us; speedup 1.0000x reference)
//
#include <hip/hip_runtime.h>

// ---------------------------------------------------------------------------
// MultilayerGRU  B=64 S=1024 I=128 H=512 L=3 O=128
//   1. transpose+convert X -> Xt[(t*64+b), i] bf16; convert weights to bf16
//   2. per layer, per 256-step chunk: P{z,r,g} = A @ Wx^T  (MFMA GEMMs)
//   3. per chunk: persistent-style recurrence kernel (plain launch, 128 WGs
//      all co-resident), Wh slices in LDS, cross-WG exchange of u=r*h and h
//      via device-scope release/acquire flags; h carried across chunks in
//      fp32 hstate.
//   4. Y = H2 @ Wy^T + by  (fp32 out)
// Workspace footprint ~132 MiB (round-1 layout was ~276 MiB -> suspected
// ws overflow / memory fault).
// ---------------------------------------------------------------------------

typedef float f32x4 __attribute__((ext_vector_type(4)));
typedef __bf16 bf16x8 __attribute__((ext_vector_type(8)));

#define CT 256   // timesteps per chunk
#define CC 16    // H-columns per workgroup slice

__device__ __forceinline__ unsigned short f2bf(float x) {
  unsigned int u = __builtin_bit_cast(unsigned int, x);
  u += 0x7fffu + ((u >> 16) & 1u);   // round-to-nearest-even
  return (unsigned short)(u >> 16);
}
__device__ __forceinline__ float bf2f(unsigned short h) {
  unsigned int u = ((unsigned int)h) << 16;
  return __builtin_bit_cast(float, u);
}
__device__ __forceinline__ f32x4 mfma16(int4 a, int4 b, f32x4 c) {
  return __builtin_amdgcn_mfma_f32_16x16x32_bf16(
      __builtin_bit_cast(bf16x8, a), __builtin_bit_cast(bf16x8, b), c, 0, 0, 0);
}
__device__ __forceinline__ float sig_(float x) { return 1.0f / (1.0f + __expf(-x)); }
__device__ __forceinline__ float tanh_(float x) {
  float ax = fabsf(x);
  float e  = __expf(2.0f * ax);          // inf-safe: e=inf -> t=1
  float t  = 1.0f - 2.0f / (e + 1.0f);
  return x < 0.0f ? -t : t;
}

// ---------------------------------------------------------------------------
// fp32 -> bf16 convert (flat)
// ---------------------------------------------------------------------------
__global__ void cvt_bf16(const float* __restrict__ src, unsigned short* __restrict__ dst, int n4) {
  int i = blockIdx.x * blockDim.x + threadIdx.x;
  if (i < n4) {
    float4 v = *(const float4*)(src + (size_t)i * 4);
    ushort4 o;
    o.x = f2bf(v.x); o.y = f2bf(v.y); o.z = f2bf(v.z); o.w = f2bf(v.w);
    *(ushort4*)(dst + (size_t)i * 4) = o;
  }
}

// X (64,1024,128) f32  ->  Xt row (t*64+b), 128 bf16
__global__ void xt_k(const float* __restrict__ X, unsigned short* __restrict__ Xt) {
  int idx = blockIdx.x * 256 + threadIdx.x;   // 2,097,152 total
  int i4 = idx & 31, rest = idx >> 5;
  int t = rest & 1023, b = rest >> 10;
  float4 v = *(const float4*)(X + (size_t)(b * 1024 + t) * 128 + i4 * 4);
  ushort4 o;
  o.x = f2bf(v.x); o.y = f2bf(v.y); o.z = f2bf(v.z); o.w = f2bf(v.w);
  *(ushort4*)(Xt + (size_t)(t * 64 + b) * 128 + i4 * 4) = o;
}

// ---------------------------------------------------------------------------
// C[M,N] = A[M,K] @ W[N,K]^T   (A,W bf16 row-major)
// mode 0: C bf16, row identity
// mode 2: C fp32 + bias, row remap m=(t*64+b) -> out row b*1024+t  (final Y)
// ---------------------------------------------------------------------------
__global__ __launch_bounds__(256)
void gemm_bt(const unsigned short* __restrict__ A, const unsigned short* __restrict__ W,
             void* __restrict__ Cout, const float* __restrict__ bias,
             int M, int N, int K, int mode) {
  __shared__ unsigned short As[128][72];
  __shared__ unsigned short Bs[128][72];
  const int tid  = threadIdx.x;
  const int lane = tid & 63;
  const int wave = tid >> 6;
  const int wr = wave >> 1, wc = wave & 1;
  const int m0 = blockIdx.x * 128, n0 = blockIdx.y * 128;

  f32x4 acc[4][4];
  for (int i = 0; i < 4; i++)
    for (int j = 0; j < 4; j++) acc[i][j] = f32x4{0.f, 0.f, 0.f, 0.f};

  for (int k0 = 0; k0 < K; k0 += 64) {
    int4 va[4], vb[4];
#pragma unroll
    for (int it = 0; it < 4; it++) {
      int q = tid + it * 256;          // 128 rows x 8 chunks of 8 bf16
      int r = q >> 3, kc = q & 7;
      va[it] = *(const int4*)(A + (size_t)(m0 + r) * K + k0 + kc * 8);
      vb[it] = *(const int4*)(W + (size_t)(n0 + r) * K + k0 + kc * 8);
    }
    __syncthreads();
#pragma unroll
    for (int it = 0; it < 4; it++) {
      int q = tid + it * 256;
      int r = q >> 3, kc = q & 7;
      *(int4*)&As[r][kc * 8] = va[it];
      *(int4*)&Bs[r][kc * 8] = vb[it];
    }
    __syncthreads();
#pragma unroll
    for (int kc = 0; kc < 2; kc++) {
      int koff = kc * 32 + (lane >> 4) * 8;
      int4 af[4], bfr[4];
#pragma unroll
      for (int mt = 0; mt < 4; mt++) af[mt]  = *(const int4*)&As[wr * 64 + mt * 16 + (lane & 15)][koff];
#pragma unroll
      for (int nt = 0; nt < 4; nt++) bfr[nt] = *(const int4*)&Bs[wc * 64 + nt * 16 + (lane & 15)][koff];
#pragma unroll
      for (int mt = 0; mt < 4; mt++)
#pragma unroll
        for (int nt = 0; nt < 4; nt++)
          acc[mt][nt] = mfma16(af[mt], bfr[nt], acc[mt][nt]);
    }
  }

#pragma unroll
  for (int mt = 0; mt < 4; mt++)
#pragma unroll
    for (int nt = 0; nt < 4; nt++)
#pragma unroll
      for (int rg = 0; rg < 4; rg++) {
        int m = m0 + wr * 64 + mt * 16 + (lane >> 4) * 4 + rg;
        int n = n0 + wc * 64 + nt * 16 + (lane & 15);
        float v = acc[mt][nt][rg];
        if (mode == 0) {
          ((unsigned short*)Cout)[(size_t)m * N + n] = f2bf(v);
        } else {
          ((float*)Cout)[(size_t)((m & 63) * 1024 + (m >> 6)) * N + n] = v + bias[n];
        }
      }
}

// ---------------------------------------------------------------------------
// Recurrence over one 256-step chunk. 128 WGs = 4 batch-groups x 32 col-slices.
// 3 waves: wave0 -> r & u=r*h publish, wave1 -> z, wave2 -> g & hn publish.
// Plain launch: 128 blocks x 192 thr x ~52KB LDS is trivially co-resident.
// ---------------------------------------------------------------------------
__device__ __forceinline__ void poll_ge(const int* f, int need) {
  int lane = threadIdx.x & 63;
  int v = need;
  if (lane < 32) v = __hip_atomic_load((int*)(f + lane), __ATOMIC_ACQUIRE, __HIP_MEMORY_SCOPE_AGENT);
  while (__any(v < need)) {
    __builtin_amdgcn_s_sleep(1);
    if (lane < 32) v = __hip_atomic_load((int*)(f + lane), __ATOMIC_ACQUIRE, __HIP_MEMORY_SCOPE_AGENT);
  }
}

__global__ __launch_bounds__(192)
void gru_rec(const float* __restrict__ Whz, const float* __restrict__ Whr,
             const float* __restrict__ Whg,
             const float* __restrict__ bz, const float* __restrict__ br,
             const float* __restrict__ bg,
             const unsigned short* __restrict__ Pz, const unsigned short* __restrict__ Pr,
             const unsigned short* __restrict__ Pg,   // chunk-local (CT,B,H) bf16
             const float* __restrict__ h0,            // (B, L, H) fp32 original
             float* __restrict__ hstate,              // (B, H) fp32 carry
             unsigned short* __restrict__ Hbuf,       // (S, B, H) bf16 full
             unsigned short* __restrict__ hbc,        // 2 slots x (B,H) bf16
             unsigned short* __restrict__ ubc,        // (B,H) bf16
             int* __restrict__ hflag, int* __restrict__ uflag,  // (4,32)
             float* __restrict__ hidout,              // (B, L, H) fp32
             int layer, int tokbase, int tstart) {
  const int bid  = blockIdx.x;
  const int g    = bid & 3;          // batch group (16 rows)
  const int mem  = bid >> 2;         // col slice 0..31
  const int cbase = mem * CC;
  const int tid  = threadIdx.x;
  const int lane = tid & 63;
  const int wave = tid >> 6;

  __shared__ unsigned short Ws[3][CC][520];   // z, r, g weight slices (bf16)
  __shared__ float hloc[16][CC + 1];
  __shared__ float zbuf[16][CC + 1];
  __shared__ float bsh[3][CC];

  // ---- stage weights fp32 -> bf16 LDS ----
  const float* wsrc[3] = { Whz + (size_t)layer * 512 * 512,
                           Whr + (size_t)layer * 512 * 512,
                           Whg + (size_t)layer * 512 * 512 };
  for (int mtx = 0; mtx < 3; mtx++) {
    const float* src = wsrc[mtx] + (size_t)cbase * 512;
    for (int q = tid; q < CC * 128; q += 192) {
      int c = q >> 7, kq = (q & 127) * 4;
      float4 v = *(const float4*)(src + c * 512 + kq);
      Ws[mtx][c][kq + 0] = f2bf(v.x);
      Ws[mtx][c][kq + 1] = f2bf(v.y);
      Ws[mtx][c][kq + 2] = f2bf(v.z);
      Ws[mtx][c][kq + 3] = f2bf(v.w);
    }
  }
  if (tid < CC) {
    bsh[0][tid] = bz[(size_t)layer * 512 + cbase + tid];
    bsh[1][tid] = br[(size_t)layer * 512 + cbase + tid];
    bsh[2][tid] = bg[(size_t)layer * 512 + cbase + tid];
  }
  // ---- init h state + publish into hbc slot 0 ----
  for (int q = tid; q < 16 * CC; q += 192) {
    int row = q >> 4, c = q & 15;
    int b = g * 16 + row;
    float v = (tstart == 0)
                ? h0[(size_t)b * 1536 + layer * 512 + cbase + c]
                : hstate[(size_t)b * 512 + cbase + c];
    hloc[row][c] = v;
    hbc[b * 512 + cbase + c] = f2bf(v);   // slot 0
  }
  __threadfence();
  __syncthreads();
  if (tid == 0)
    __hip_atomic_store(&hflag[g * 32 + mem], tokbase + 1, __ATOMIC_RELEASE, __HIP_MEMORY_SCOPE_AGENT);

  const int* hfg = hflag + g * 32;
  const int* ufg = uflag + g * 32;
  const int myflag = g * 32 + mem;
  const int row4 = (lane >> 4);     // quad 0..3
  const int ccol = lane & 15;

  for (int tl = 0; tl < CT; tl++) {
    // prefetch this wave's P values (independent of h -> early issue)
    float pval[4];
    {
      const unsigned short* Psrc = (wave == 0) ? Pr : (wave == 1) ? Pz : Pg;
#pragma unroll
      for (int rg = 0; rg < 4; rg++) {
        int b = g * 16 + row4 * 4 + rg;
        pval[rg] = bf2f(Psrc[(size_t)tl * 32768 + b * 512 + cbase + ccol]);
      }
    }
    f32x4 accg = f32x4{0.f, 0.f, 0.f, 0.f};

    if (wave <= 1) {
      // -------- phase 1: r (wave0) / z (wave1) --------
      poll_ge(hfg, tokbase + 1 + tl);
      const unsigned short* hrow = hbc + (size_t)(tl & 1) * 32768 + (g * 16 + ccol) * 512 + row4 * 8;
      int4 af[16];
#pragma unroll
      for (int kc = 0; kc < 16; kc++) af[kc] = *(const int4*)(hrow + kc * 32);
      const unsigned short* wrow = &Ws[wave == 0 ? 1 : 0][ccol][row4 * 8];
      f32x4 a0 = f32x4{0.f, 0.f, 0.f, 0.f}, a1 = f32x4{0.f, 0.f, 0.f, 0.f};
#pragma unroll
      for (int kc = 0; kc < 16; kc += 2) {
        int4 b0 = *(const int4*)(wrow + kc * 32);
        int4 b1 = *(const int4*)(wrow + (kc + 1) * 32);
        a0 = mfma16(af[kc], b0, a0);
        a1 = mfma16(af[kc + 1], b1, a1);
      }
      f32x4 acc = a0 + a1;
      if (wave == 0) {
#pragma unroll
        for (int rg = 0; rg < 4; rg++) {
          int rrow = row4 * 4 + rg;
          float rv = sig_(acc[rg] + pval[rg] + bsh[1][ccol]);
          float uv = rv * hloc[rrow][ccol];
          ubc[(g * 16 + rrow) * 512 + cbase + ccol] = f2bf(uv);
        }
        __threadfence();
        if (lane == 0)
          __hip_atomic_store((int*)&uflag[myflag], tokbase + 1 + tl, __ATOMIC_RELEASE, __HIP_MEMORY_SCOPE_AGENT);
      } else {
#pragma unroll
        for (int rg = 0; rg < 4; rg++) {
          int rrow = row4 * 4 + rg;
          zbuf[rrow][ccol] = sig_(acc[rg] + pval[rg] + bsh[0][ccol]);
        }
      }
    } else {
      // -------- phase 2 pre: g pre-activation (wave2) --------
      poll_ge(ufg, tokbase + 1 + tl);
      const unsigned short* urow = ubc + (g * 16 + ccol) * 512 + row4 * 8;
      int4 uf[16];
#pragma unroll
      for (int kc = 0; kc < 16; kc++) uf[kc] = *(const int4*)(urow + kc * 32);
      const unsigned short* wrow = &Ws[2][ccol][row4 * 8];
      f32x4 a0 = f32x4{0.f, 0.f, 0.f, 0.f}, a1 = f32x4{0.f, 0.f, 0.f, 0.f};
#pragma unroll
      for (int kc = 0; kc < 16; kc += 2) {
        int4 b0 = *(const int4*)(wrow + kc * 32);
        int4 b1 = *(const int4*)(wrow + (kc + 1) * 32);
        a0 = mfma16(uf[kc], b0, a0);
        a1 = mfma16(uf[kc + 1], b1, a1);
      }
      accg = a0 + a1;
    }
    __syncthreads();   // z written (wave1) before wave2 consumes it
    if (wave == 2) {
      unsigned short* hw = hbc + (size_t)((tl + 1) & 1) * 32768;
      int tg = tstart + tl;
#pragma unroll
      for (int rg = 0; rg < 4; rg++) {
        int rrow = row4 * 4 + rg;
        int b = g * 16 + rrow;
        float gv = tanh_(accg[rg] + pval[rg] + bsh[2][ccol]);
        float z  = zbuf[rrow][ccol];
        float h  = hloc[rrow][ccol];
        float hn = z * h + (1.0f - z) * gv;
        hloc[rrow][ccol] = hn;
        unsigned short hb = f2bf(hn);
        hw[b * 512 + cbase + ccol] = hb;
        Hbuf[(size_t)tg * 32768 + b * 512 + cbase + ccol] = hb;
        if (tl == CT - 1) {
          hstate[(size_t)b * 512 + cbase + ccol] = hn;
          if (tg == 1023)
            hidout[(size_t)b * 1536 + layer * 512 + cbase + ccol] = hn;
        }
      }
      __threadfence();
      if (lane == 0)
        __hip_atomic_store((int*)&hflag[myflag], tokbase + 2 + tl, __ATOMIC_RELEASE, __HIP_MEMORY_SCOPE_AGENT);
    }
  }
}

// ---------------------------------------------------------------------------
// launcher
// ---------------------------------------------------------------------------
extern "C" void kernel_launch(void* const* d_in, const int* in_sizes, int n_in,
                              void* d_out, int out_size, void* d_ws, size_t ws_size,
                              hipStream_t stream) {
  const float* X    = (const float*)d_in[0];
  const float* H0   = (const float*)d_in[1];
  const float* Wx0z = (const float*)d_in[2];
  const float* Wx0r = (const float*)d_in[3];
  const float* Wx0g = (const float*)d_in[4];
  const float* Wxz  = (const float*)d_in[5];
  const float* Wxr  = (const float*)d_in[6];
  const float* Wxg  = (const float*)d_in[7];
  const float* Whz  = (const float*)d_in[8];
  const float* Whr  = (const float*)d_in[9];
  const float* Whg  = (const float*)d_in[10];
  const float* bz   = (const float*)d_in[11];
  const float* br   = (const float*)d_in[12];
  const float* bg   = (const float*)d_in[13];
  const float* Wy   = (const float*)d_in[14];
  const float* by   = (const float*)d_in[15];

  char* w = (char*)d_ws;
  unsigned short* Xt    = (unsigned short*)(w + 0);          // 16,777,216
  unsigned short* Wx0zb = (unsigned short*)(w + 16777216);   // 131,072
  unsigned short* Wx0rb = (unsigned short*)(w + 16908288);
  unsigned short* Wx0gb = (unsigned short*)(w + 17039360);
  unsigned short* Wxzb  = (unsigned short*)(w + 17170432);   // 1,048,576
  unsigned short* Wxrb  = (unsigned short*)(w + 18219008);
  unsigned short* Wxgb  = (unsigned short*)(w + 19267584);
  unsigned short* Wyb   = (unsigned short*)(w + 20316160);   // 131,072
  unsigned short* Pz    = (unsigned short*)(w + 20447232);   // 16,777,216 each
  unsigned short* Pr    = (unsigned short*)(w + 37224448);
  unsigned short* Pg    = (unsigned short*)(w + 54001664);
  unsigned short* Hb    = (unsigned short*)(w + 70778880);   // 67,108,864
  float*          hst   = (float*)(w + 137887744);           // 131,072
  unsigned short* hbc   = (unsigned short*)(w + 138018816);  // 131,072
  unsigned short* ubc   = (unsigned short*)(w + 138149888);  // 65,536
  int* hflag            = (int*)(w + 138215424);
  int* uflag            = (int*)(w + 138217472);
  // end ~138,219,520 bytes (~132 MiB)

  hipMemsetAsync(hflag, 0, 4096, stream);

  auto cvt = [&](const float* s, unsigned short* d, int n) {
    int n4 = n / 4;
    cvt_bf16<<<dim3((n4 + 255) / 256), dim3(256), 0, stream>>>(s, d, n4);
  };
  xt_k<<<dim3(8192), dim3(256), 0, stream>>>(X, Xt);
  cvt(Wx0z, Wx0zb, 65536);
  cvt(Wx0r, Wx0rb, 65536);
  cvt(Wx0g, Wx0gb, 65536);
  cvt(Wxz, Wxzb, 524288);
  cvt(Wxr, Wxrb, 524288);
  cvt(Wxg, Wxgb, 524288);
  cvt(Wy, Wyb, 65536);

  float* hidout = (float*)d_out + 8388608;

  for (int layer = 0; layer < 3; layer++) {
    for (int chunk = 0; chunk < 4; chunk++) {
      int tstart = chunk * CT;
      const unsigned short *Ap, *wz, *wr_, *wg;
      int K;
      if (layer == 0) {
        Ap = Xt + (size_t)tstart * 64 * 128;
        wz = Wx0zb; wr_ = Wx0rb; wg = Wx0gb; K = 128;
      } else {
        Ap = Hb + (size_t)tstart * 64 * 512;
        wz = Wxzb + (size_t)(layer - 1) * 262144;
        wr_ = Wxrb + (size_t)(layer - 1) * 262144;
        wg = Wxgb + (size_t)(layer - 1) * 262144;
        K = 512;
      }
      gemm_bt<<<dim3(128, 4), 256, 0, stream>>>(Ap, wz,  Pz, (const float*)nullptr, 16384, 512, K, 0);
      gemm_bt<<<dim3(128, 4), 256, 0, stream>>>(Ap, wr_, Pr, (const float*)nullptr, 16384, 512, K, 0);
      gemm_bt<<<dim3(128, 4), 256, 0, stream>>>(Ap, wg,  Pg, (const float*)nullptr, 16384, 512, K, 0);

      int tokbase = (layer * 4 + chunk) * 512;
      gru_rec<<<dim3(128), dim3(192), 0, stream>>>(
          Whz, Whr, Whg, bz, br, bg, Pz, Pr, Pg, H0, hst, Hb, hbc, ubc,
          hflag, uflag, hidout, layer, tokbase, tstart);
    }
  }

  // Y = H2 @ Wy^T + by  -> (B,S,O) fp32
  gemm_bt<<<dim3(512, 1), 256, 0, stream>>>(Hb, Wyb, d_out, by, 65536, 128, 512, 2);
}

// Round 3
// 22645.392 us; speedup vs baseline: 3.6337x; 3.6337x over previous
//
#include <hip/hip_runtime.h>

// ---------------------------------------------------------------------------
// MultilayerGRU  B=64 S=1024 I=128 H=512 L=3 O=128
//   1. transpose+convert X -> Xt[(t*64+b), i] bf16; convert weights to bf16
//   2. per layer, per 256-step chunk: P{z,r,g} = A @ Wx^T  (MFMA GEMMs)
//   3. per chunk: persistent-style recurrence kernel (128 WGs co-resident),
//      Wh slices in LDS, cross-WG exchange of u=r*h and h via RELAXED
//      write-through atomics (sc1, coherence-point) + vmcnt(0)-ordered flag
//      stores. NO __threadfence / NO acquire -> no L2 wbl2/inv storms
//      (round-2 counters: 26us/step, MfmaUtil 0.15% -> fence-bound).
//   4. Y = H2 @ Wy^T + by  (fp32 out)
// ---------------------------------------------------------------------------

typedef float f32x4 __attribute__((ext_vector_type(4)));
typedef __bf16 bf16x8 __attribute__((ext_vector_type(8)));

#define CT 256   // timesteps per chunk
#define CC 16    // H-columns per workgroup slice

__device__ __forceinline__ unsigned short f2bf(float x) {
  unsigned int u = __builtin_bit_cast(unsigned int, x);
  u += 0x7fffu + ((u >> 16) & 1u);   // round-to-nearest-even
  return (unsigned short)(u >> 16);
}
__device__ __forceinline__ float bf2f(unsigned short h) {
  unsigned int u = ((unsigned int)h) << 16;
  return __builtin_bit_cast(float, u);
}
__device__ __forceinline__ f32x4 mfma16(int4 a, int4 b, f32x4 c) {
  return __builtin_amdgcn_mfma_f32_16x16x32_bf16(
      __builtin_bit_cast(bf16x8, a), __builtin_bit_cast(bf16x8, b), c, 0, 0, 0);
}
__device__ __forceinline__ float sig_(float x) { return 1.0f / (1.0f + __expf(-x)); }
__device__ __forceinline__ float tanh_(float x) {
  float ax = fabsf(x);
  float e  = __expf(2.0f * ax);          // inf-safe
  float t  = 1.0f - 2.0f / (e + 1.0f);
  return x < 0.0f ? -t : t;
}

// ---- write-through (coherence-point) atomic helpers: no cache maintenance ----
__device__ __forceinline__ unsigned long long ld_wt64(const unsigned long long* p) {
  return __hip_atomic_load(p, __ATOMIC_RELAXED, __HIP_MEMORY_SCOPE_AGENT);
}
__device__ __forceinline__ void st_wt16(unsigned short* p, unsigned short v) {
  __hip_atomic_store(p, v, __ATOMIC_RELAXED, __HIP_MEMORY_SCOPE_AGENT);
}
__device__ __forceinline__ void st_flag(int* p, int v) {
  // order: prior write-through stores acked at coherence point, then flag
  asm volatile("s_waitcnt vmcnt(0)" ::: "memory");
  __hip_atomic_store(p, v, __ATOMIC_RELAXED, __HIP_MEMORY_SCOPE_AGENT);
}

// ---------------------------------------------------------------------------
// fp32 -> bf16 convert (flat)
// ---------------------------------------------------------------------------
__global__ void cvt_bf16(const float* __restrict__ src, unsigned short* __restrict__ dst, int n4) {
  int i = blockIdx.x * blockDim.x + threadIdx.x;
  if (i < n4) {
    float4 v = *(const float4*)(src + (size_t)i * 4);
    ushort4 o;
    o.x = f2bf(v.x); o.y = f2bf(v.y); o.z = f2bf(v.z); o.w = f2bf(v.w);
    *(ushort4*)(dst + (size_t)i * 4) = o;
  }
}

// X (64,1024,128) f32  ->  Xt row (t*64+b), 128 bf16
__global__ void xt_k(const float* __restrict__ X, unsigned short* __restrict__ Xt) {
  int idx = blockIdx.x * 256 + threadIdx.x;
  int i4 = idx & 31, rest = idx >> 5;
  int t = rest & 1023, b = rest >> 10;
  float4 v = *(const float4*)(X + (size_t)(b * 1024 + t) * 128 + i4 * 4);
  ushort4 o;
  o.x = f2bf(v.x); o.y = f2bf(v.y); o.z = f2bf(v.z); o.w = f2bf(v.w);
  *(ushort4*)(Xt + (size_t)(t * 64 + b) * 128 + i4 * 4) = o;
}

// ---------------------------------------------------------------------------
// C[M,N] = A[M,K] @ W[N,K]^T   (A,W bf16 row-major)
// mode 0: C bf16, row identity
// mode 2: C fp32 + bias, row remap m=(t*64+b) -> out row b*1024+t  (final Y)
// ---------------------------------------------------------------------------
__global__ __launch_bounds__(256)
void gemm_bt(const unsigned short* __restrict__ A, const unsigned short* __restrict__ W,
             void* __restrict__ Cout, const float* __restrict__ bias,
             int M, int N, int K, int mode) {
  __shared__ unsigned short As[128][72];
  __shared__ unsigned short Bs[128][72];
  const int tid  = threadIdx.x;
  const int lane = tid & 63;
  const int wave = tid >> 6;
  const int wr = wave >> 1, wc = wave & 1;
  const int m0 = blockIdx.x * 128, n0 = blockIdx.y * 128;

  f32x4 acc[4][4];
  for (int i = 0; i < 4; i++)
    for (int j = 0; j < 4; j++) acc[i][j] = f32x4{0.f, 0.f, 0.f, 0.f};

  for (int k0 = 0; k0 < K; k0 += 64) {
    int4 va[4], vb[4];
#pragma unroll
    for (int it = 0; it < 4; it++) {
      int q = tid + it * 256;
      int r = q >> 3, kc = q & 7;
      va[it] = *(const int4*)(A + (size_t)(m0 + r) * K + k0 + kc * 8);
      vb[it] = *(const int4*)(W + (size_t)(n0 + r) * K + k0 + kc * 8);
    }
    __syncthreads();
#pragma unroll
    for (int it = 0; it < 4; it++) {
      int q = tid + it * 256;
      int r = q >> 3, kc = q & 7;
      *(int4*)&As[r][kc * 8] = va[it];
      *(int4*)&Bs[r][kc * 8] = vb[it];
    }
    __syncthreads();
#pragma unroll
    for (int kc = 0; kc < 2; kc++) {
      int koff = kc * 32 + (lane >> 4) * 8;
      int4 af[4], bfr[4];
#pragma unroll
      for (int mt = 0; mt < 4; mt++) af[mt]  = *(const int4*)&As[wr * 64 + mt * 16 + (lane & 15)][koff];
#pragma unroll
      for (int nt = 0; nt < 4; nt++) bfr[nt] = *(const int4*)&Bs[wc * 64 + nt * 16 + (lane & 15)][koff];
#pragma unroll
      for (int mt = 0; mt < 4; mt++)
#pragma unroll
        for (int nt = 0; nt < 4; nt++)
          acc[mt][nt] = mfma16(af[mt], bfr[nt], acc[mt][nt]);
    }
  }

#pragma unroll
  for (int mt = 0; mt < 4; mt++)
#pragma unroll
    for (int nt = 0; nt < 4; nt++)
#pragma unroll
      for (int rg = 0; rg < 4; rg++) {
        int m = m0 + wr * 64 + mt * 16 + (lane >> 4) * 4 + rg;
        int n = n0 + wc * 64 + nt * 16 + (lane & 15);
        float v = acc[mt][nt][rg];
        if (mode == 0) {
          ((unsigned short*)Cout)[(size_t)m * N + n] = f2bf(v);
        } else {
          ((float*)Cout)[(size_t)((m & 63) * 1024 + (m >> 6)) * N + n] = v + bias[n];
        }
      }
}

// ---------------------------------------------------------------------------
// Recurrence over one 256-step chunk. 128 WGs = 4 batch-groups x 32 col-slices.
// 3 waves: wave0 -> r & u=r*h publish, wave1 -> z, wave2 -> g & hn publish.
// ---------------------------------------------------------------------------
__device__ __forceinline__ void poll_ge(const int* f, int need) {
  int lane = threadIdx.x & 63;
  int v = need;
  if (lane < 32) v = __hip_atomic_load((int*)(f + lane), __ATOMIC_RELAXED, __HIP_MEMORY_SCOPE_AGENT);
  while (__any(v < need)) {
    __builtin_amdgcn_s_sleep(1);
    if (lane < 32) v = __hip_atomic_load((int*)(f + lane), __ATOMIC_RELAXED, __HIP_MEMORY_SCOPE_AGENT);
  }
}

__device__ __forceinline__ void load_frags16(const unsigned short* base, int4* af) {
  const unsigned long long* p = (const unsigned long long*)base;
#pragma unroll
  for (int kc = 0; kc < 16; kc++) {
    unsigned long long lo = ld_wt64(p + kc * 8);
    unsigned long long hi = ld_wt64(p + kc * 8 + 1);
    af[kc] = make_int4((int)(unsigned int)lo, (int)(unsigned int)(lo >> 32),
                       (int)(unsigned int)hi, (int)(unsigned int)(hi >> 32));
  }
}

__global__ __launch_bounds__(192)
void gru_rec(const float* __restrict__ Whz, const float* __restrict__ Whr,
             const float* __restrict__ Whg,
             const float* __restrict__ bz, const float* __restrict__ br,
             const float* __restrict__ bg,
             const unsigned short* __restrict__ Pz, const unsigned short* __restrict__ Pr,
             const unsigned short* __restrict__ Pg,   // chunk-local (CT,B,H) bf16
             const float* __restrict__ h0,            // (B, L, H) fp32 original
             float* __restrict__ hstate,              // (B, H) fp32 carry
             unsigned short* __restrict__ Hbuf,       // (S, B, H) bf16 full
             unsigned short* __restrict__ hbc,        // 2 slots x (B,H) bf16
             unsigned short* __restrict__ ubc,        // (B,H) bf16
             int* __restrict__ hflag, int* __restrict__ uflag,  // (4,32)
             float* __restrict__ hidout,              // (B, L, H) fp32
             int layer, int tokbase, int tstart) {
  const int bid  = blockIdx.x;
  const int g    = bid & 3;          // batch group (16 rows)
  const int mem  = bid >> 2;         // col slice 0..31
  const int cbase = mem * CC;
  const int tid  = threadIdx.x;
  const int lane = tid & 63;
  const int wave = tid >> 6;

  __shared__ unsigned short Ws[3][CC][520];   // z, r, g weight slices (bf16)
  __shared__ float hloc[16][CC + 1];
  __shared__ float zbuf[16][CC + 1];
  __shared__ float bsh[3][CC];

  // ---- stage weights fp32 -> bf16 LDS ----
  const float* wsrc[3] = { Whz + (size_t)layer * 512 * 512,
                           Whr + (size_t)layer * 512 * 512,
                           Whg + (size_t)layer * 512 * 512 };
  for (int mtx = 0; mtx < 3; mtx++) {
    const float* src = wsrc[mtx] + (size_t)cbase * 512;
    for (int q = tid; q < CC * 128; q += 192) {
      int c = q >> 7, kq = (q & 127) * 4;
      float4 v = *(const float4*)(src + c * 512 + kq);
      Ws[mtx][c][kq + 0] = f2bf(v.x);
      Ws[mtx][c][kq + 1] = f2bf(v.y);
      Ws[mtx][c][kq + 2] = f2bf(v.z);
      Ws[mtx][c][kq + 3] = f2bf(v.w);
    }
  }
  if (tid < CC) {
    bsh[0][tid] = bz[(size_t)layer * 512 + cbase + tid];
    bsh[1][tid] = br[(size_t)layer * 512 + cbase + tid];
    bsh[2][tid] = bg[(size_t)layer * 512 + cbase + tid];
  }
  // ---- init h state + publish into hbc slot 0 (write-through stores) ----
  for (int q = tid; q < 16 * CC; q += 192) {
    int row = q >> 4, c = q & 15;
    int b = g * 16 + row;
    float v = (tstart == 0)
                ? h0[(size_t)b * 1536 + layer * 512 + cbase + c]
                : hstate[(size_t)b * 512 + cbase + c];
    hloc[row][c] = v;
    st_wt16(&hbc[b * 512 + cbase + c], f2bf(v));   // slot 0
  }
  __syncthreads();   // implicit per-wave vmcnt(0) drain before barrier
  if (tid == 0)
    __hip_atomic_store(&hflag[g * 32 + mem], tokbase + 1, __ATOMIC_RELAXED, __HIP_MEMORY_SCOPE_AGENT);

  const int* hfg = hflag + g * 32;
  const int* ufg = uflag + g * 32;
  const int myflag = g * 32 + mem;
  const int row4 = (lane >> 4);     // quad 0..3
  const int ccol = lane & 15;

  for (int tl = 0; tl < CT; tl++) {
    // prefetch this wave's P values (independent of h -> early issue)
    float pval[4];
    {
      const unsigned short* Psrc = (wave == 0) ? Pr : (wave == 1) ? Pz : Pg;
#pragma unroll
      for (int rg = 0; rg < 4; rg++) {
        int b = g * 16 + row4 * 4 + rg;
        pval[rg] = bf2f(Psrc[(size_t)tl * 32768 + b * 512 + cbase + ccol]);
      }
    }
    f32x4 accg = f32x4{0.f, 0.f, 0.f, 0.f};

    if (wave <= 1) {
      // -------- phase 1: r (wave0) / z (wave1) --------
      poll_ge(hfg, tokbase + 1 + tl);
      const unsigned short* hrow = hbc + (size_t)(tl & 1) * 32768 + (g * 16 + ccol) * 512 + row4 * 8;
      int4 af[16];
      load_frags16(hrow, af);
      const unsigned short* wrow = &Ws[wave == 0 ? 1 : 0][ccol][row4 * 8];
      f32x4 a0 = f32x4{0.f, 0.f, 0.f, 0.f}, a1 = f32x4{0.f, 0.f, 0.f, 0.f};
#pragma unroll
      for (int kc = 0; kc < 16; kc += 2) {
        int4 b0 = *(const int4*)(wrow + kc * 32);
        int4 b1 = *(const int4*)(wrow + (kc + 1) * 32);
        a0 = mfma16(af[kc], b0, a0);
        a1 = mfma16(af[kc + 1], b1, a1);
      }
      f32x4 acc = a0 + a1;
      if (wave == 0) {
#pragma unroll
        for (int rg = 0; rg < 4; rg++) {
          int rrow = row4 * 4 + rg;
          float rv = sig_(acc[rg] + pval[rg] + bsh[1][ccol]);
          float uv = rv * hloc[rrow][ccol];
          st_wt16(&ubc[(g * 16 + rrow) * 512 + cbase + ccol], f2bf(uv));
        }
        if (lane == 0) { /* whole-wave stores above share this wave's vmcnt */ }
        st_flag_guard:
        if (lane == 0)
          st_flag((int*)&uflag[myflag], tokbase + 1 + tl);
        else
          asm volatile("s_waitcnt vmcnt(0)" ::: "memory");
      } else {
#pragma unroll
        for (int rg = 0; rg < 4; rg++) {
          int rrow = row4 * 4 + rg;
          zbuf[rrow][ccol] = sig_(acc[rg] + pval[rg] + bsh[0][ccol]);
        }
      }
    } else {
      // -------- phase 2 pre: g pre-activation (wave2) --------
      poll_ge(ufg, tokbase + 1 + tl);
      const unsigned short* urow = ubc + (g * 16 + ccol) * 512 + row4 * 8;
      int4 uf[16];
      load_frags16(urow, uf);
      const unsigned short* wrow = &Ws[2][ccol][row4 * 8];
      f32x4 a0 = f32x4{0.f, 0.f, 0.f, 0.f}, a1 = f32x4{0.f, 0.f, 0.f, 0.f};
#pragma unroll
      for (int kc = 0; kc < 16; kc += 2) {
        int4 b0 = *(const int4*)(wrow + kc * 32);
        int4 b1 = *(const int4*)(wrow + (kc + 1) * 32);
        a0 = mfma16(uf[kc], b0, a0);
        a1 = mfma16(uf[kc + 1], b1, a1);
      }
      accg = a0 + a1;
    }
    __syncthreads();   // z written (wave1) before wave2 consumes it
    if (wave == 2) {
      unsigned short* hw = hbc + (size_t)((tl + 1) & 1) * 32768;
      int tg = tstart + tl;
#pragma unroll
      for (int rg = 0; rg < 4; rg++) {
        int rrow = row4 * 4 + rg;
        int b = g * 16 + rrow;
        float gv = tanh_(accg[rg] + pval[rg] + bsh[2][ccol]);
        float z  = zbuf[rrow][ccol];
        float h  = hloc[rrow][ccol];
        float hn = z * h + (1.0f - z) * gv;
        hloc[rrow][ccol] = hn;
        unsigned short hb = f2bf(hn);
        st_wt16(&hw[b * 512 + cbase + ccol], hb);
        Hbuf[(size_t)tg * 32768 + b * 512 + cbase + ccol] = hb;
        if (tl == CT - 1) {
          hstate[(size_t)b * 512 + cbase + ccol] = hn;
          if (tg == 1023)
            hidout[(size_t)b * 1536 + layer * 512 + cbase + ccol] = hn;
        }
      }
      if (lane == 0)
        st_flag((int*)&hflag[myflag], tokbase + 2 + tl);
      else
        asm volatile("s_waitcnt vmcnt(0)" ::: "memory");
    }
  }
}

// ---------------------------------------------------------------------------
// launcher
// ---------------------------------------------------------------------------
extern "C" void kernel_launch(void* const* d_in, const int* in_sizes, int n_in,
                              void* d_out, int out_size, void* d_ws, size_t ws_size,
                              hipStream_t stream) {
  const float* X    = (const float*)d_in[0];
  const float* H0   = (const float*)d_in[1];
  const float* Wx0z = (const float*)d_in[2];
  const float* Wx0r = (const float*)d_in[3];
  const float* Wx0g = (const float*)d_in[4];
  const float* Wxz  = (const float*)d_in[5];
  const float* Wxr  = (const float*)d_in[6];
  const float* Wxg  = (const float*)d_in[7];
  const float* Whz  = (const float*)d_in[8];
  const float* Whr  = (const float*)d_in[9];
  const float* Whg  = (const float*)d_in[10];
  const float* bz   = (const float*)d_in[11];
  const float* br   = (const float*)d_in[12];
  const float* bg   = (const float*)d_in[13];
  const float* Wy   = (const float*)d_in[14];
  const float* by   = (const float*)d_in[15];

  char* w = (char*)d_ws;
  unsigned short* Xt    = (unsigned short*)(w + 0);          // 16,777,216
  unsigned short* Wx0zb = (unsigned short*)(w + 16777216);   // 131,072
  unsigned short* Wx0rb = (unsigned short*)(w + 16908288);
  unsigned short* Wx0gb = (unsigned short*)(w + 17039360);
  unsigned short* Wxzb  = (unsigned short*)(w + 17170432);   // 1,048,576
  unsigned short* Wxrb  = (unsigned short*)(w + 18219008);
  unsigned short* Wxgb  = (unsigned short*)(w + 19267584);
  unsigned short* Wyb   = (unsigned short*)(w + 20316160);   // 131,072
  unsigned short* Pz    = (unsigned short*)(w + 20447232);   // 16,777,216 each
  unsigned short* Pr    = (unsigned short*)(w + 37224448);
  unsigned short* Pg    = (unsigned short*)(w + 54001664);
  unsigned short* Hb    = (unsigned short*)(w + 70778880);   // 67,108,864
  float*          hst   = (float*)(w + 137887744);           // 131,072
  unsigned short* hbc   = (unsigned short*)(w + 138018816);  // 131,072
  unsigned short* ubc   = (unsigned short*)(w + 138149888);  // 65,536
  int* hflag            = (int*)(w + 138215424);
  int* uflag            = (int*)(w + 138217472);

  hipMemsetAsync(hflag, 0, 4096, stream);

  auto cvt = [&](const float* s, unsigned short* d, int n) {
    int n4 = n / 4;
    cvt_bf16<<<dim3((n4 + 255) / 256), dim3(256), 0, stream>>>(s, d, n4);
  };
  xt_k<<<dim3(8192), dim3(256), 0, stream>>>(X, Xt);
  cvt(Wx0z, Wx0zb, 65536);
  cvt(Wx0r, Wx0rb, 65536);
  cvt(Wx0g, Wx0gb, 65536);
  cvt(Wxz, Wxzb, 524288);
  cvt(Wxr, Wxrb, 524288);
  cvt(Wxg, Wxgb, 524288);
  cvt(Wy, Wyb, 65536);

  float* hidout = (float*)d_out + 8388608;

  for (int layer = 0; layer < 3; layer++) {
    for (int chunk = 0; chunk < 4; chunk++) {
      int tstart = chunk * CT;
      const unsigned short *Ap, *wz, *wr_, *wg;
      int K;
      if (layer == 0) {
        Ap = Xt + (size_t)tstart * 64 * 128;
        wz = Wx0zb; wr_ = Wx0rb; wg = Wx0gb; K = 128;
      } else {
        Ap = Hb + (size_t)tstart * 64 * 512;
        wz = Wxzb + (size_t)(layer - 1) * 262144;
        wr_ = Wxrb + (size_t)(layer - 1) * 262144;
        wg = Wxgb + (size_t)(layer - 1) * 262144;
        K = 512;
      }
      gemm_bt<<<dim3(128, 4), 256, 0, stream>>>(Ap, wz,  Pz, (const float*)nullptr, 16384, 512, K, 0);
      gemm_bt<<<dim3(128, 4), 256, 0, stream>>>(Ap, wr_, Pr, (const float*)nullptr, 16384, 512, K, 0);
      gemm_bt<<<dim3(128, 4), 256, 0, stream>>>(Ap, wg,  Pg, (const float*)nullptr, 16384, 512, K, 0);

      int tokbase = (layer * 4 + chunk) * 512;
      gru_rec<<<dim3(128), dim3(192), 0, stream>>>(
          Whz, Whr, Whg, bz, br, bg, Pz, Pr, Pg, H0, hst, Hb, hbc, ubc,
          hflag, uflag, hidout, layer, tokbase, tstart);
    }
  }

  // Y = H2 @ Wy^T + by  -> (B,S,O) fp32
  gemm_bt<<<dim3(512, 1), 256, 0, stream>>>(Hb, Wyb, d_out, by, 65536, 128, 512, 2);
}